// Round 11
// baseline (1699.883 us; speedup 1.0000x reference)
//
#include <hip/hip_runtime.h>
#include <hip/hip_bf16.h>
#include <cstdint>

typedef __attribute__((ext_vector_type(8))) short short8;
typedef __attribute__((ext_vector_type(4))) float float4v;
typedef __attribute__((ext_vector_type(2))) unsigned int uint2v;

#define LOG2E 1.44269504088896340736f
#define LN2   0.69314718055994530942f

#if __has_builtin(__builtin_amdgcn_exp2f)
__device__ __forceinline__ float fexp2(float x){ return __builtin_amdgcn_exp2f(x); }
#else
__device__ __forceinline__ float fexp2(float x){ return exp2f(x); }
#endif
#if __has_builtin(__builtin_amdgcn_logf)
__device__ __forceinline__ float flog2(float x){ return __builtin_amdgcn_logf(x); }
#else
__device__ __forceinline__ float flog2(float x){ return log2f(x); }
#endif

// hhat = log2(1 + 2^zhat); biases pre-scaled by log2e so GEMM on hhat yields
// the next zhat directly (ln2 * log2e == 1 cancels).
__device__ __forceinline__ float softplus_hat(float zh){
  return flog2(1.0f + fexp2(zh));
}

// pack two positive floats to bf16x2 via truncation (RTZ) — 2 VALU ops.
__device__ __forceinline__ unsigned int pack_bf16(float lo, float hi){
  return (__builtin_bit_cast(unsigned int, hi) & 0xFFFF0000u) |
         (__builtin_bit_cast(unsigned int, lo) >> 16);
}
__device__ __forceinline__ unsigned short bf16_trunc(float f){
  return (unsigned short)(__builtin_bit_cast(unsigned int, f) >> 16);
}

#define HSTRIDE 260   // 520B row stride: b64 C-writes hit each bank once/16 lanes

// ---------------------------------------------------------------------------
// Pre-pass: Wh [S,4,256,256] fp32 -> bf16 slabs Wt[s*4+l][kb][n][ki]
// (kb=k/32, ki=k%32). Slab row n = W^T[n][.] -> read as the MFMA A-operand:
// lanes {n,n+16,n+32,n+48} cover row n's 64B contiguously (1KB/wave-instr L2).
// ---------------------------------------------------------------------------
__global__ void convert_wh(const float* __restrict__ Wh,
                           unsigned short* __restrict__ Wt){
  int e = blockIdx.x * 256 + threadIdx.x;          // 0 .. 2^21-1
  int n  = e & 255;
  int k  = (e >> 8) & 255;
  int sl = e >> 16;
  float v = Wh[e];
  __hip_bfloat16 h = __float2bfloat16(v);
  Wt[(sl << 16) + ((k >> 5) << 13) + (n << 5) + (k & 31)] =
      __builtin_bit_cast(unsigned short, h);
}

__device__ __forceinline__ float4v bf16_mfma(short8 a, short8 b, float4v c){
  return __builtin_amdgcn_mfma_f32_16x16x32_bf16(a, b, c, 0, 0, 0);
}

// ---------------------------------------------------------------------------
// One layer's K-loop, OPERAND-SWAPPED: A = W^T (global slab, rotating 3-slot
// prefetch with continuous phase slot=(8L+kb)%3 — at kb=5..7 the freed slot
// prefetches the next layer's kb 0..2, hiding refill under the barrier),
// B = h (LDS, double-buffered, pure-immediate addressing).
// Result D = z^T: lane holds m=lane&15 (+16*mi) fixed, n=q*4+reg consecutive
// -> epilogue stores are vectorizable b64 (the whole point of the swap).
// ---------------------------------------------------------------------------
template<int L>
__device__ __forceinline__ void hidden_mfma(
    const unsigned short* __restrict__ bbase0,   // slab + lane offset (A-op)
    const unsigned short* __restrict__ aptr,     // h_lds + lane base (B-op)
    short8 (&bq)[3][4], float4v (&acc)[4][4])
{
  const unsigned short* bb = bbase0 + L * 65536;
  const unsigned short* bn = bbase0 + (L + 1) * 65536;

  short8 a0[4], a1[4];
  #pragma unroll
  for (int mi = 0; mi < 4; ++mi)
    a0[mi] = *(const short8*)(aptr + mi * 4160);          // mi*16*HSTRIDE

  #pragma unroll
  for (int kb = 0; kb < 8; ++kb) {
    short8* cur = (kb & 1) ? a1 : a0;
    short8* nxt = (kb & 1) ? a0 : a1;
    if (kb < 7) {                                  // h prefetch depth 1 (LDS)
      #pragma unroll
      for (int mi = 0; mi < 4; ++mi)
        nxt[mi] = *(const short8*)(aptr + (kb + 1) * 32 + mi * 4160);
    }
    const int slot = (8 * L + kb) % 3;             // compile-time (unrolled)
    #pragma unroll
    for (int mi = 0; mi < 4; ++mi)
      #pragma unroll
      for (int ni = 0; ni < 4; ++ni)
        acc[mi][ni] = bf16_mfma(bq[slot][ni], cur[mi], acc[mi][ni]);  // A=W^T!
    if (kb < 5) {                                  // A-slab depth-3, this layer
      #pragma unroll
      for (int ni = 0; ni < 4; ++ni)
        bq[slot][ni] = *(const short8*)(bb + (kb + 3) * 8192 + ni * 512);
    } else if (L < 3) {                            // next layer's kb 0..2
      #pragma unroll
      for (int ni = 0; ni < 4; ++ni)
        bq[slot][ni] = *(const short8*)(bn + (kb - 5) * 8192 + ni * 512);
    }
  }
}

// ---------------------------------------------------------------------------
// Fused MLP: 4 waves, wave tile 64m x 64n, one series/block, s = blk&7 (XCD-
// pinned slabs). h row-major [m][HSTRIDE] in LDS; reads AND writes are
// contiguous per lane thanks to the z^T operand swap.
// ---------------------------------------------------------------------------
__global__ __launch_bounds__(256, 2) void series_mlp(
    const float* __restrict__ coords,
    const float* __restrict__ W0, const float* __restrict__ b0,
    const float* __restrict__ bh,
    const float* __restrict__ Wout, const float* __restrict__ bout,
    const unsigned short* __restrict__ Wt,
    float* __restrict__ out)
{
  __shared__ __align__(16) unsigned short h_lds[64 * HSTRIDE];   // 33280 B
  __shared__ float cbuf[192];
  __shared__ float red2[256];

  const int tid  = threadIdx.x;
  const int lane = tid & 63;
  const int wn   = tid >> 6;
  const int s    = blockIdx.x & 7;          // series == XCD
  const int m0   = (blockIdx.x >> 3) * 64;  // 3125*64 == 200000 exactly

  if (tid < 192) cbuf[tid] = coords[m0 * 3 + tid];
  __syncthreads();

  // ---------------- layer 0: K=3, pure VALU, float4 coord reads ----------------
  {
    const int c  = tid;
    const float w0 = W0[(s * 3 + 0) * 256 + c] * LOG2E;
    const float w1 = W0[(s * 3 + 1) * 256 + c] * LOG2E;
    const float w2 = W0[(s * 3 + 2) * 256 + c] * LOG2E;
    const float bb = b0[s * 256 + c] * LOG2E;
    const float4v* c4 = (const float4v*)cbuf;
    #pragma unroll
    for (int j = 0; j < 16; ++j) {             // 4 rows per iter, 3 b128 reads
      float4v x0 = c4[j * 3 + 0];
      float4v x1 = c4[j * 3 + 1];
      float4v x2 = c4[j * 3 + 2];
      float z0 = fmaf(x0.z, w2, fmaf(x0.y, w1, fmaf(x0.x, w0, bb)));
      float z1 = fmaf(x1.y, w2, fmaf(x1.x, w1, fmaf(x0.w, w0, bb)));
      float z2 = fmaf(x2.x, w2, fmaf(x1.w, w1, fmaf(x1.z, w0, bb)));
      float z3 = fmaf(x2.w, w2, fmaf(x2.z, w1, fmaf(x2.y, w0, bb)));
      h_lds[(4 * j + 0) * HSTRIDE + c] = bf16_trunc(softplus_hat(z0));
      h_lds[(4 * j + 1) * HSTRIDE + c] = bf16_trunc(softplus_hat(z1));
      h_lds[(4 * j + 2) * HSTRIDE + c] = bf16_trunc(softplus_hat(z2));
      h_lds[(4 * j + 3) * HSTRIDE + c] = bf16_trunc(softplus_hat(z3));
    }
  }
  __syncthreads();

  const int colb = (wn << 6) + (lane & 15);   // A-slab row block (n index)
  const int q    = lane >> 4;
  // B-op (h) lane base: row m=lane&15, k-octet q. Imm: mi*4160 + kb*32.
  const unsigned short* aptr = h_lds + (lane & 15) * HSTRIDE + q * 8;
  // C-store lane base: row m=lane&15, col n = wn*64 + q*4. Imm: mi*4160+ni*16.
  unsigned short* cptr = h_lds + (lane & 15) * HSTRIDE + (wn << 6) + (q << 2);

  const unsigned short* bbase0 = Wt + ((s << 2) << 16) + (colb << 5) + (q << 3);

  short8 bq[3][4];
  #pragma unroll
  for (int i = 0; i < 3; ++i)
    #pragma unroll
    for (int ni = 0; ni < 4; ++ni)
      bq[i][ni] = *(const short8*)(bbase0 + i * 8192 + ni * 512);

  float4v acc[4][4];
  const float* bh_s = bh + (s << 10);
  const int nb = (wn << 6) + (q << 2);        // lane's first n (per ni: +16ni)

  // ---------------- hidden layers 0..2 ----------------
  #define HIDDEN_LAYER(L)                                                     \
  {                                                                           \
    float4v bias4[4];                                                         \
    _Pragma("unroll")                                                         \
    for (int ni = 0; ni < 4; ++ni) {                                          \
      float4v b = *(const float4v*)&bh_s[L * 256 + nb + ni * 16];             \
      b.x *= LOG2E; b.y *= LOG2E; b.z *= LOG2E; b.w *= LOG2E;                 \
      bias4[ni] = b;                                                          \
    }                                                                         \
    _Pragma("unroll")                                                         \
    for (int mi = 0; mi < 4; ++mi)                                            \
      _Pragma("unroll")                                                       \
      for (int ni = 0; ni < 4; ++ni)                                          \
        acc[mi][ni] = bias4[ni];                                              \
    hidden_mfma<L>(bbase0, aptr, bq, acc);                                    \
    uint2v pk[4][4];                                                          \
    _Pragma("unroll")                                                         \
    for (int mi = 0; mi < 4; ++mi)                                            \
      _Pragma("unroll")                                                       \
      for (int ni = 0; ni < 4; ++ni) {                                        \
        float4v v = acc[mi][ni];                                              \
        float s0 = softplus_hat(v.x), s1 = softplus_hat(v.y);                 \
        float s2 = softplus_hat(v.z), s3 = softplus_hat(v.w);                 \
        pk[mi][ni] = (uint2v){pack_bf16(s0, s1), pack_bf16(s2, s3)};          \
      }                                                                       \
    __syncthreads();                                                          \
    _Pragma("unroll")                                                         \
    for (int mi = 0; mi < 4; ++mi)                                            \
      _Pragma("unroll")                                                       \
      for (int ni = 0; ni < 4; ++ni)                                          \
        *(uint2v*)(cptr + mi * 4160 + ni * 16) = pk[mi][ni];                  \
    __syncthreads();                                                          \
  }

  HIDDEN_LAYER(0)
  HIDDEN_LAYER(1)
  HIDDEN_LAYER(2)
  #undef HIDDEN_LAYER

  // ------- layer 3: MFMA + fused output (dot with Wout in regs) -------
  {
    float4v bias4[4];
    #pragma unroll
    for (int ni = 0; ni < 4; ++ni) {
      float4v b = *(const float4v*)&bh_s[3 * 256 + nb + ni * 16];
      b.x *= LOG2E; b.y *= LOG2E; b.z *= LOG2E; b.w *= LOG2E;
      bias4[ni] = b;
    }
    #pragma unroll
    for (int mi = 0; mi < 4; ++mi)
      #pragma unroll
      for (int ni = 0; ni < 4; ++ni)
        acc[mi][ni] = bias4[ni];

    hidden_mfma<3>(bbase0, aptr, bq, acc);

    float4v wv4[4];
    #pragma unroll
    for (int ni = 0; ni < 4; ++ni)
      wv4[ni] = *(const float4v*)&Wout[(s << 8) + nb + ni * 16];

    float pd[4] = {0.f, 0.f, 0.f, 0.f};          // per-mi partial dot (m fixed)
    #pragma unroll
    for (int mi = 0; mi < 4; ++mi)
      #pragma unroll
      for (int ni = 0; ni < 4; ++ni) {
        float4v v = acc[mi][ni];
        pd[mi] = fmaf(softplus_hat(v.x), wv4[ni].x,
                 fmaf(softplus_hat(v.y), wv4[ni].y,
                 fmaf(softplus_hat(v.z), wv4[ni].z,
                 fmaf(softplus_hat(v.w), wv4[ni].w, pd[mi]))));
      }

    // reduce over q (lanes 16 apart hold different n-quarters of the same m)
    #pragma unroll
    for (int mi = 0; mi < 4; ++mi) {
      pd[mi] += __shfl_xor(pd[mi], 16, 64);
      pd[mi] += __shfl_xor(pd[mi], 32, 64);
    }
    if (lane < 16) {
      #pragma unroll
      for (int mi = 0; mi < 4; ++mi)
        red2[(wn << 6) + mi * 16 + lane] = pd[mi];
    }
    __syncthreads();

    if (tid < 64) {
      float tot = red2[tid] + red2[64 + tid] + red2[128 + tid] + red2[192 + tid];
      out[(m0 + tid) * 8 + s] = fmaf(LN2, tot, bout[s]);  // undo log2-domain
    }
  }
}

// ---------------------------------------------------------------------------
// Fallback (scratch-free), fp32 VALU — only if ws_size < 4 MiB.
// ---------------------------------------------------------------------------
__global__ __launch_bounds__(256) void series_mlp_slow(
    const float* __restrict__ coords,
    const float* __restrict__ W0, const float* __restrict__ b0,
    const float* __restrict__ Wh, const float* __restrict__ bh,
    const float* __restrict__ Wout, const float* __restrict__ bout,
    float* __restrict__ out)
{
  __shared__ float hh[64 * 256];
  __shared__ float cbuf[192];
  __shared__ float red[256];
  const int tid = threadIdx.x;
  const int s   = blockIdx.y;
  const int m0  = blockIdx.x * 64;

  if (tid < 192) cbuf[tid] = coords[m0 * 3 + tid];
  __syncthreads();
  {
    const float w0 = W0[(s * 3 + 0) * 256 + tid];
    const float w1 = W0[(s * 3 + 1) * 256 + tid];
    const float w2 = W0[(s * 3 + 2) * 256 + tid];
    const float bb = b0[s * 256 + tid];
    for (int m = 0; m < 64; ++m) {
      float z = fmaf(cbuf[m * 3 + 2], w2,
                fmaf(cbuf[m * 3 + 1], w1,
                fmaf(cbuf[m * 3 + 0], w0, bb)));
      hh[m * 256 + tid] = LN2 * softplus_hat(z * LOG2E);
    }
  }
  __syncthreads();

  for (int l = 0; l < 4; ++l) {
    const float* W = Wh + (((s << 2) + l) << 16);
    const float bb = bh[((s << 2) + l) * 256 + tid];
    float acc[64];
    #pragma unroll
    for (int m = 0; m < 64; ++m) acc[m] = bb;
    for (int kc = 0; kc < 64; ++kc) {
      float w0 = W[(kc * 4 + 0) * 256 + tid];
      float w1 = W[(kc * 4 + 1) * 256 + tid];
      float w2 = W[(kc * 4 + 2) * 256 + tid];
      float w3 = W[(kc * 4 + 3) * 256 + tid];
      #pragma unroll
      for (int m = 0; m < 64; ++m) {
        float4v hv = *(const float4v*)&hh[m * 256 + kc * 4];
        acc[m] = fmaf(hv.w, w3, fmaf(hv.z, w2,
                 fmaf(hv.y, w1, fmaf(hv.x, w0, acc[m]))));
      }
    }
    __syncthreads();
    #pragma unroll
    for (int m = 0; m < 64; ++m)
      hh[m * 256 + tid] = LN2 * softplus_hat(acc[m] * LOG2E);
    __syncthreads();
  }
  {
    const int m = tid >> 2, qq = tid & 3;
    const float* wv = Wout + (s << 8);
    float sum = 0.f;
    for (int i = 0; i < 16; ++i) {
      int kk = (qq << 6) + ((((tid & 15) + i) << 2) & 63);
      float4v hv = *(const float4v*)&hh[m * 256 + kk];
      sum += hv.x * wv[kk] + hv.y * wv[kk + 1] + hv.z * wv[kk + 2] + hv.w * wv[kk + 3];
    }
    red[tid] = sum;
    __syncthreads();
    if (tid < 64)
      out[(m0 + tid) * 8 + s] =
          red[tid * 4] + red[tid * 4 + 1] + red[tid * 4 + 2] + red[tid * 4 + 3] + bout[s];
  }
}

extern "C" void kernel_launch(void* const* d_in, const int* in_sizes, int n_in,
                              void* d_out, int out_size, void* d_ws, size_t ws_size,
                              hipStream_t stream) {
  const float* coords = (const float*)d_in[0];
  const float* W0     = (const float*)d_in[1];
  const float* b0     = (const float*)d_in[2];
  const float* Wh     = (const float*)d_in[3];
  const float* bh     = (const float*)d_in[4];
  const float* Wout   = (const float*)d_in[5];
  const float* bout   = (const float*)d_in[6];
  float* out = (float*)d_out;

  const size_t WT_BYTES = (size_t)8 * 4 * 256 * 256 * 2;   // 4 MiB bf16 slabs
  if (ws_size >= WT_BYTES) {
    unsigned short* Wt = (unsigned short*)d_ws;
    convert_wh<<<8192, 256, 0, stream>>>(Wh, Wt);
    series_mlp<<<dim3(25000), dim3(256), 0, stream>>>(
        coords, W0, b0, bh, Wout, bout, Wt, out);
  } else {
    series_mlp_slow<<<dim3(3125, 8), dim3(256), 0, stream>>>(
        coords, W0, b0, Wh, bh, Wout, bout, out);
  }
  // second tuple output: echo coords
  hipMemcpyAsync(out + (size_t)200000 * 8, coords,
                 (size_t)200000 * 3 * sizeof(float),
                 hipMemcpyDeviceToDevice, stream);
}

// Round 12
// 1651.503 us; speedup vs baseline: 1.0293x; 1.0293x over previous
//
#include <hip/hip_runtime.h>
#include <hip/hip_bf16.h>
#include <cstdint>

typedef __attribute__((ext_vector_type(8))) short short8;
typedef __attribute__((ext_vector_type(4))) float float4v;

#define LOG2E 1.44269504088896340736f
#define LN2   0.69314718055994530942f

#if __has_builtin(__builtin_amdgcn_exp2f)
__device__ __forceinline__ float fexp2(float x){ return __builtin_amdgcn_exp2f(x); }
#else
__device__ __forceinline__ float fexp2(float x){ return exp2f(x); }
#endif
#if __has_builtin(__builtin_amdgcn_logf)
__device__ __forceinline__ float flog2(float x){ return __builtin_amdgcn_logf(x); }
#else
__device__ __forceinline__ float flog2(float x){ return log2f(x); }
#endif

// hhat = log2(1 + 2^zhat); biases pre-scaled by log2e so GEMM on hhat yields
// the next zhat directly (ln2 * log2e == 1 cancels).
__device__ __forceinline__ float softplus_hat(float zh){
  return flog2(1.0f + fexp2(zh));
}

// softplus output > 0 -> truncation (RTZ) to bf16 is a 1-instr shift.
__device__ __forceinline__ unsigned short bf16_trunc(float f){
  return (unsigned short)(__builtin_bit_cast(unsigned int, f) >> 16);
}

// h row stride. 268 (not 264): C-write q-row spacing 4*268*2B = 536 dwords
// = 24 mod 32 -> the four q-rows' 8-dword spans tile banks b,b+8,b+16,b+24
// exactly -> conflict-free writes (264 gave 16 mod 32 -> 4-way conflicts,
// the 5.12e7 SQ_LDS_BANK_CONFLICT of round 8). A-reads: 134 dwords/row
// = 6 mod 32 -> <=2-way aliasing (free, m136).
#define HSTRIDE 268
#define HROW16  (16 * HSTRIDE)   // 4288 elems

// ---------------------------------------------------------------------------
// Pre-pass: Wh [S,4,256,256] fp32 -> bf16 slabs Wt[s*4+l][kb][n][ki]
// (kb = k/32, ki = k%32). B-frags are read from GLOBAL: lanes {n,n+16,n+32,
// n+48} of a wave cover row n's 64B contiguously -> 1KB/wave-instr from L2.
// ---------------------------------------------------------------------------
__global__ void convert_wh(const float* __restrict__ Wh,
                           unsigned short* __restrict__ Wt){
  int e = blockIdx.x * 256 + threadIdx.x;          // 0 .. 2^21-1
  int n  = e & 255;
  int k  = (e >> 8) & 255;
  int sl = e >> 16;
  float v = Wh[e];
  __hip_bfloat16 h = __float2bfloat16(v);
  Wt[(sl << 16) + ((k >> 5) << 13) + (n << 5) + (k & 31)] =
      __builtin_bit_cast(unsigned short, h);
}

__device__ __forceinline__ float4v bf16_mfma(short8 a, short8 b, float4v c){
  return __builtin_amdgcn_mfma_f32_16x16x32_bf16(a, b, c, 0, 0, 0);
}

// ---------------------------------------------------------------------------
// One layer's K-loop (round-8 schedule, untouched): A = h (LDS, double-
// buffered, pure-immediate addressing), B = W slab (global, rotating 3-slot
// prefetch, continuous phase slot=(8L+kb)%3; at kb=5..7 the freed slot
// prefetches the next layer's kb 0..2 so the refill hides under the barrier).
// ---------------------------------------------------------------------------
template<int L>
__device__ __forceinline__ void hidden_mfma(
    const unsigned short* __restrict__ bbase0,   // slab base + lane offset
    const unsigned short* __restrict__ aptr,     // h_lds + lane A-base
    short8 (&bq)[3][4], float4v (&acc)[4][4])
{
  const unsigned short* bb = bbase0 + L * 65536;
  const unsigned short* bn = bbase0 + (L + 1) * 65536;

  short8 a0[4], a1[4];
  #pragma unroll
  for (int mi = 0; mi < 4; ++mi)
    a0[mi] = *(const short8*)(aptr + mi * HROW16);

  #pragma unroll
  for (int kb = 0; kb < 8; ++kb) {
    short8* cur = (kb & 1) ? a1 : a0;
    short8* nxt = (kb & 1) ? a0 : a1;
    if (kb < 7) {                                  // A prefetch depth 1 (LDS)
      #pragma unroll
      for (int mi = 0; mi < 4; ++mi)
        nxt[mi] = *(const short8*)(aptr + (kb + 1) * 32 + mi * HROW16);
    }
    const int slot = (8 * L + kb) % 3;             // compile-time (unrolled)
    #pragma unroll
    for (int mi = 0; mi < 4; ++mi)
      #pragma unroll
      for (int ni = 0; ni < 4; ++ni)
        acc[mi][ni] = bf16_mfma(cur[mi], bq[slot][ni], acc[mi][ni]);
    if (kb < 5) {                                  // B depth-3, this layer
      #pragma unroll
      for (int ni = 0; ni < 4; ++ni)
        bq[slot][ni] = *(const short8*)(bb + (kb + 3) * 8192 + ni * 512);
    } else if (L < 3) {                            // next layer's kb 0..2
      #pragma unroll
      for (int ni = 0; ni < 4; ++ni)
        bq[slot][ni] = *(const short8*)(bn + (kb - 5) * 8192 + ni * 512);
    }
  }
}

// ---------------------------------------------------------------------------
// Fused MLP (round-8 champion + HSTRIDE 268): 4 waves, wave tile 64m x 64n,
// one series/block, s = blk&7 (XCD-pinned weight slabs). h row-major
// [m][HSTRIDE] in LDS; all addressing one base reg + immediate.
// ---------------------------------------------------------------------------
__global__ __launch_bounds__(256, 2) void series_mlp(
    const float* __restrict__ coords,
    const float* __restrict__ W0, const float* __restrict__ b0,
    const float* __restrict__ bh,
    const float* __restrict__ Wout, const float* __restrict__ bout,
    const unsigned short* __restrict__ Wt,
    float* __restrict__ out)
{
  __shared__ __align__(16) unsigned short h_lds[64 * HSTRIDE];   // 34304 B
  __shared__ float cbuf[192];

  const int tid  = threadIdx.x;
  const int lane = tid & 63;
  const int wave = tid >> 6;
  const int s    = blockIdx.x & 7;          // series == XCD
  const int m0   = (blockIdx.x >> 3) * 64;  // 3125*64 == 200000 exactly

  if (tid < 192) cbuf[tid] = coords[m0 * 3 + tid];
  __syncthreads();

  // ---------------- layer 0: K=3, pure VALU, float4 coord reads ----------------
  {
    const int c  = tid;
    const float w0 = W0[(s * 3 + 0) * 256 + c] * LOG2E;
    const float w1 = W0[(s * 3 + 1) * 256 + c] * LOG2E;
    const float w2 = W0[(s * 3 + 2) * 256 + c] * LOG2E;
    const float bb = b0[s * 256 + c] * LOG2E;
    const float4v* c4 = (const float4v*)cbuf;
    #pragma unroll
    for (int j = 0; j < 16; ++j) {             // 4 rows per iter, 3 b128 reads
      float4v x0 = c4[j * 3 + 0];
      float4v x1 = c4[j * 3 + 1];
      float4v x2 = c4[j * 3 + 2];
      float z0 = fmaf(x0.z, w2, fmaf(x0.y, w1, fmaf(x0.x, w0, bb)));
      float z1 = fmaf(x1.y, w2, fmaf(x1.x, w1, fmaf(x0.w, w0, bb)));
      float z2 = fmaf(x2.x, w2, fmaf(x1.w, w1, fmaf(x1.z, w0, bb)));
      float z3 = fmaf(x2.w, w2, fmaf(x2.z, w1, fmaf(x2.y, w0, bb)));
      h_lds[(4 * j + 0) * HSTRIDE + c] = bf16_trunc(softplus_hat(z0));
      h_lds[(4 * j + 1) * HSTRIDE + c] = bf16_trunc(softplus_hat(z1));
      h_lds[(4 * j + 2) * HSTRIDE + c] = bf16_trunc(softplus_hat(z2));
      h_lds[(4 * j + 3) * HSTRIDE + c] = bf16_trunc(softplus_hat(z3));
    }
  }
  __syncthreads();

  const int colb = (wave << 6) + (lane & 15);
  const int q    = lane >> 4;
  // A-frag lane base: row (lane&15), octet q. Imm: mi*HROW16 + kb*32 elems.
  const unsigned short* aptr = h_lds + (lane & 15) * HSTRIDE + q * 8;
  // C-write lane base: row q*4, col colb. Imm: mi*HROW16 + r*HSTRIDE + ni*16.
  unsigned short* cptr = h_lds + (q * 4) * HSTRIDE + colb;

  const unsigned short* bbase0 = Wt + ((s << 2) << 16) + (colb << 5) + (q << 3);

  short8 bq[3][4];
  #pragma unroll
  for (int i = 0; i < 3; ++i)
    #pragma unroll
    for (int ni = 0; ni < 4; ++ni)
      bq[i][ni] = *(const short8*)(bbase0 + i * 8192 + ni * 512);

  float4v acc[4][4];
  const float* bh_s = bh + (s << 10);

  // ---------------- hidden layers 0..2 ----------------
  #define HIDDEN_LAYER(L)                                                     \
  {                                                                           \
    float bias[4];                                                            \
    _Pragma("unroll")                                                         \
    for (int ni = 0; ni < 4; ++ni)                                            \
      bias[ni] = bh_s[L * 256 + colb + ni * 16] * LOG2E;                      \
    _Pragma("unroll")                                                         \
    for (int mi = 0; mi < 4; ++mi)                                            \
      _Pragma("unroll")                                                       \
      for (int ni = 0; ni < 4; ++ni)                                          \
        acc[mi][ni] = (float4v){bias[ni], bias[ni], bias[ni], bias[ni]};      \
    hidden_mfma<L>(bbase0, aptr, bq, acc);                                    \
    _Pragma("unroll")                                                         \
    for (int mi = 0; mi < 4; ++mi)                                            \
      _Pragma("unroll")                                                       \
      for (int ni = 0; ni < 4; ++ni) {                                        \
        float4v v = acc[mi][ni];                                              \
        _Pragma("unroll")                                                     \
        for (int r = 0; r < 4; ++r) v[r] = softplus_hat(v[r]);                \
        acc[mi][ni] = v;                                                      \
      }                                                                       \
    __syncthreads();                                                          \
    _Pragma("unroll")                                                         \
    for (int mi = 0; mi < 4; ++mi)                                            \
      _Pragma("unroll")                                                       \
      for (int ni = 0; ni < 4; ++ni) {                                        \
        float4v v = acc[mi][ni];                                              \
        _Pragma("unroll")                                                     \
        for (int r = 0; r < 4; ++r)                                           \
          cptr[mi * HROW16 + r * HSTRIDE + ni * 16] = bf16_trunc(v[r]);       \
      }                                                                       \
    __syncthreads();                                                          \
  }

  HIDDEN_LAYER(0)
  HIDDEN_LAYER(1)
  HIDDEN_LAYER(2)
  #undef HIDDEN_LAYER

  // ------- layer 3: MFMA + fused output (dot with Wout, no h write-back) -------
  {
    float bias[4];
    #pragma unroll
    for (int ni = 0; ni < 4; ++ni)
      bias[ni] = bh_s[3 * 256 + colb + ni * 16] * LOG2E;
    #pragma unroll
    for (int mi = 0; mi < 4; ++mi)
      #pragma unroll
      for (int ni = 0; ni < 4; ++ni)
        acc[mi][ni] = (float4v){bias[ni], bias[ni], bias[ni], bias[ni]};

    hidden_mfma<3>(bbase0, aptr, bq, acc);

    // softplus + per-lane partial dot over this wave's 4 cols (fp32 h4).
    float wv[4];
    #pragma unroll
    for (int ni = 0; ni < 4; ++ni)
      wv[ni] = Wout[(s << 8) + colb + ni * 16];
    float p[16];
    #pragma unroll
    for (int i = 0; i < 16; ++i) p[i] = 0.f;
    #pragma unroll
    for (int mi = 0; mi < 4; ++mi)
      #pragma unroll
      for (int ni = 0; ni < 4; ++ni) {
        float4v v = acc[mi][ni];
        #pragma unroll
        for (int r = 0; r < 4; ++r)
          p[mi * 4 + r] = fmaf(softplus_hat(v[r]), wv[ni], p[mi * 4 + r]);
      }

    __syncthreads();                    // all A-reads done; h_lds reusable
    float* red = (float*)h_lds;         // 64 rows x 64 partials, stride-68 pad
    #pragma unroll
    for (int mi = 0; mi < 4; ++mi)
      #pragma unroll
      for (int r = 0; r < 4; ++r) {
        int row = mi * 16 + (q << 2) + r;
        red[row * 68 + (wave << 4) + (lane & 15)] = p[mi * 4 + r];
      }
    __syncthreads();

    if (tid < 64) {
      const float4v* rr = (const float4v*)&red[tid * 68];
      float4v a = rr[0];
      #pragma unroll
      for (int i = 1; i < 16; ++i) {
        float4v b = rr[i];
        a.x += b.x; a.y += b.y; a.z += b.z; a.w += b.w;
      }
      float tot = (a.x + a.y) + (a.z + a.w);
      out[(m0 + tid) * 8 + s] = fmaf(LN2, tot, bout[s]);  // undo log2-domain
    }
  }
}

// ---------------------------------------------------------------------------
// Fallback (scratch-free), fp32 VALU — only if ws_size < 4 MiB.
// ---------------------------------------------------------------------------
__global__ __launch_bounds__(256) void series_mlp_slow(
    const float* __restrict__ coords,
    const float* __restrict__ W0, const float* __restrict__ b0,
    const float* __restrict__ Wh, const float* __restrict__ bh,
    const float* __restrict__ Wout, const float* __restrict__ bout,
    float* __restrict__ out)
{
  __shared__ float hh[64 * 256];
  __shared__ float cbuf[192];
  __shared__ float red[256];
  const int tid = threadIdx.x;
  const int s   = blockIdx.y;
  const int m0  = blockIdx.x * 64;

  if (tid < 192) cbuf[tid] = coords[m0 * 3 + tid];
  __syncthreads();
  {
    const float w0 = W0[(s * 3 + 0) * 256 + tid];
    const float w1 = W0[(s * 3 + 1) * 256 + tid];
    const float w2 = W0[(s * 3 + 2) * 256 + tid];
    const float bb = b0[s * 256 + tid];
    for (int m = 0; m < 64; ++m) {
      float z = fmaf(cbuf[m * 3 + 2], w2,
                fmaf(cbuf[m * 3 + 1], w1,
                fmaf(cbuf[m * 3 + 0], w0, bb)));
      hh[m * 256 + tid] = LN2 * softplus_hat(z * LOG2E);
    }
  }
  __syncthreads();

  for (int l = 0; l < 4; ++l) {
    const float* W = Wh + (((s << 2) + l) << 16);
    const float bb = bh[((s << 2) + l) * 256 + tid];
    float acc[64];
    #pragma unroll
    for (int m = 0; m < 64; ++m) acc[m] = bb;
    for (int kc = 0; kc < 64; ++kc) {
      float w0 = W[(kc * 4 + 0) * 256 + tid];
      float w1 = W[(kc * 4 + 1) * 256 + tid];
      float w2 = W[(kc * 4 + 2) * 256 + tid];
      float w3 = W[(kc * 4 + 3) * 256 + tid];
      #pragma unroll
      for (int m = 0; m < 64; ++m) {
        float4v hv = *(const float4v*)&hh[m * 256 + kc * 4];
        acc[m] = fmaf(hv.w, w3, fmaf(hv.z, w2,
                 fmaf(hv.y, w1, fmaf(hv.x, w0, acc[m]))));
      }
    }
    __syncthreads();
    #pragma unroll
    for (int m = 0; m < 64; ++m)
      hh[m * 256 + tid] = LN2 * softplus_hat(acc[m] * LOG2E);
    __syncthreads();
  }
  {
    const int m = tid >> 2, qq = tid & 3;
    const float* wv = Wout + (s << 8);
    float sum = 0.f;
    for (int i = 0; i < 16; ++i) {
      int kk = (qq << 6) + ((((tid & 15) + i) << 2) & 63);
      float4v hv = *(const float4v*)&hh[m * 256 + kk];
      sum += hv.x * wv[kk] + hv.y * wv[kk + 1] + hv.z * wv[kk + 2] + hv.w * wv[kk + 3];
    }
    red[tid] = sum;
    __syncthreads();
    if (tid < 64)
      out[(m0 + tid) * 8 + s] =
          red[tid * 4] + red[tid * 4 + 1] + red[tid * 4 + 2] + red[tid * 4 + 3] + bout[s];
  }
}

extern "C" void kernel_launch(void* const* d_in, const int* in_sizes, int n_in,
                              void* d_out, int out_size, void* d_ws, size_t ws_size,
                              hipStream_t stream) {
  const float* coords = (const float*)d_in[0];
  const float* W0     = (const float*)d_in[1];
  const float* b0     = (const float*)d_in[2];
  const float* Wh     = (const float*)d_in[3];
  const float* bh     = (const float*)d_in[4];
  const float* Wout   = (const float*)d_in[5];
  const float* bout   = (const float*)d_in[6];
  float* out = (float*)d_out;

  const size_t WT_BYTES = (size_t)8 * 4 * 256 * 256 * 2;   // 4 MiB bf16 slabs
  if (ws_size >= WT_BYTES) {
    unsigned short* Wt = (unsigned short*)d_ws;
    convert_wh<<<8192, 256, 0, stream>>>(Wh, Wt);
    series_mlp<<<dim3(25000), dim3(256), 0, stream>>>(
        coords, W0, b0, bh, Wout, bout, Wt, out);
  } else {
    series_mlp_slow<<<dim3(3125, 8), dim3(256), 0, stream>>>(
        coords, W0, b0, Wh, bh, Wout, bout, out);
  }
  // second tuple output: echo coords
  hipMemcpyAsync(out + (size_t)200000 * 8, coords,
                 (size_t)200000 * 3 * sizeof(float),
                 hipMemcpyDeviceToDevice, stream);
}

// Round 13
// 914.079 us; speedup vs baseline: 1.8597x; 1.8067x over previous
//
#include <hip/hip_runtime.h>
#include <hip/hip_bf16.h>
#include <cstdint>

typedef __attribute__((ext_vector_type(8))) short short8;
typedef __attribute__((ext_vector_type(4))) float float4v;

#define LOG2E 1.44269504088896340736f
#define LN2   0.69314718055994530942f

#if __has_builtin(__builtin_amdgcn_exp2f)
__device__ __forceinline__ float fexp2(float x){ return __builtin_amdgcn_exp2f(x); }
#else
__device__ __forceinline__ float fexp2(float x){ return exp2f(x); }
#endif
#if __has_builtin(__builtin_amdgcn_logf)
__device__ __forceinline__ float flog2(float x){ return __builtin_amdgcn_logf(x); }
#else
__device__ __forceinline__ float flog2(float x){ return log2f(x); }
#endif

// hhat = log2(1 + 2^zhat); biases pre-scaled by log2e so GEMM on hhat yields
// the next zhat directly (ln2 * log2e == 1 cancels).
__device__ __forceinline__ float softplus_hat(float zh){
  return flog2(1.0f + fexp2(zh));
}

// softplus output > 0 -> truncation (RTZ) to bf16 is a 1-instr shift.
__device__ __forceinline__ unsigned short bf16_trunc(float f){
  return (unsigned short)(__builtin_bit_cast(unsigned int, f) >> 16);
}

// h layout: addr(m,c) = m*264 + (m>>2)*16 + c elems (SKEWED, not plain 2D).
//  * row stride 264 elems = 528 B == 0 mod 16 -> every ds_read_b128 stays
//    16-B aligned. (R11/R12 lesson: strides 260/268 -> 8-mod-16 addresses ->
//    unaligned-b128 scalarization, +70% wall. Alignment is non-negotiable.)
//  * +16-elem skew per 4 rows: C-write q-rows (4 apart) start at dword banks
//    {0,24,16,8}+const -> disjoint 8-dword spans -> conflict-free scalar b16
//    writes at the wave64 2-lanes/bank minimum (kills round-8's 5.12e7).
//  * A-reads: 16 rows start at 4m+8(m>>2) mod 32 -> spans <=2-way (free).
// All offsets still base+immediate: A mi-step 4288 (=16*264+4*16), kb-step 32;
// C base q*1072 (=q*(4*264+16)), imms r*264 + mi*4288 + ni*16.
#define HSTRIDE 264
#define MISTEP  4288
#define HSIZE   (64 * 264 + 16 * 16)   // 17152 elems = 34304 B

// ---------------------------------------------------------------------------
// Pre-pass: Wh [S,4,256,256] fp32 -> bf16 slabs Wt[s*4+l][kb][n][ki]
// (kb = k/32, ki = k%32). B-frags are read from GLOBAL: lanes {n,n+16,n+32,
// n+48} of a wave cover row n's 64B contiguously -> 1KB/wave-instr from L2.
// ---------------------------------------------------------------------------
__global__ void convert_wh(const float* __restrict__ Wh,
                           unsigned short* __restrict__ Wt){
  int e = blockIdx.x * 256 + threadIdx.x;          // 0 .. 2^21-1
  int n  = e & 255;
  int k  = (e >> 8) & 255;
  int sl = e >> 16;
  float v = Wh[e];
  __hip_bfloat16 h = __float2bfloat16(v);
  Wt[(sl << 16) + ((k >> 5) << 13) + (n << 5) + (k & 31)] =
      __builtin_bit_cast(unsigned short, h);
}

__device__ __forceinline__ float4v bf16_mfma(short8 a, short8 b, float4v c){
  return __builtin_amdgcn_mfma_f32_16x16x32_bf16(a, b, c, 0, 0, 0);
}

// ---------------------------------------------------------------------------
// One layer's K-loop (round-8 schedule, untouched): A = h (LDS, double-
// buffered, pure-immediate addressing), B = W slab (global, rotating 3-slot
// prefetch, continuous phase slot=(8L+kb)%3; at kb=5..7 the freed slot
// prefetches the next layer's kb 0..2 so the refill hides under the barrier).
// ---------------------------------------------------------------------------
template<int L>
__device__ __forceinline__ void hidden_mfma(
    const unsigned short* __restrict__ bbase0,   // slab base + lane offset
    const unsigned short* __restrict__ aptr,     // h_lds + lane A-base
    short8 (&bq)[3][4], float4v (&acc)[4][4])
{
  const unsigned short* bb = bbase0 + L * 65536;
  const unsigned short* bn = bbase0 + (L + 1) * 65536;

  short8 a0[4], a1[4];
  #pragma unroll
  for (int mi = 0; mi < 4; ++mi)
    a0[mi] = *(const short8*)(aptr + mi * MISTEP);

  #pragma unroll
  for (int kb = 0; kb < 8; ++kb) {
    short8* cur = (kb & 1) ? a1 : a0;
    short8* nxt = (kb & 1) ? a0 : a1;
    if (kb < 7) {                                  // A prefetch depth 1 (LDS)
      #pragma unroll
      for (int mi = 0; mi < 4; ++mi)
        nxt[mi] = *(const short8*)(aptr + (kb + 1) * 32 + mi * MISTEP);
    }
    const int slot = (8 * L + kb) % 3;             // compile-time (unrolled)
    #pragma unroll
    for (int mi = 0; mi < 4; ++mi)
      #pragma unroll
      for (int ni = 0; ni < 4; ++ni)
        acc[mi][ni] = bf16_mfma(cur[mi], bq[slot][ni], acc[mi][ni]);
    if (kb < 5) {                                  // B depth-3, this layer
      #pragma unroll
      for (int ni = 0; ni < 4; ++ni)
        bq[slot][ni] = *(const short8*)(bb + (kb + 3) * 8192 + ni * 512);
    } else if (L < 3) {                            // next layer's kb 0..2
      #pragma unroll
      for (int ni = 0; ni < 4; ++ni)
        bq[slot][ni] = *(const short8*)(bn + (kb - 5) * 8192 + ni * 512);
    }
  }
}

// ---------------------------------------------------------------------------
// Fused MLP (round-8 champion + skewed h layout): 4 waves, wave tile
// 64m x 64n, one series/block, s = blk&7 (XCD-pinned weight slabs).
// ---------------------------------------------------------------------------
__global__ __launch_bounds__(256, 2) void series_mlp(
    const float* __restrict__ coords,
    const float* __restrict__ W0, const float* __restrict__ b0,
    const float* __restrict__ bh,
    const float* __restrict__ Wout, const float* __restrict__ bout,
    const unsigned short* __restrict__ Wt,
    float* __restrict__ out)
{
  __shared__ __align__(16) unsigned short h_lds[HSIZE];   // 34304 B
  __shared__ float cbuf[192];

  const int tid  = threadIdx.x;
  const int lane = tid & 63;
  const int wave = tid >> 6;
  const int s    = blockIdx.x & 7;          // series == XCD
  const int m0   = (blockIdx.x >> 3) * 64;  // 3125*64 == 200000 exactly

  if (tid < 192) cbuf[tid] = coords[m0 * 3 + tid];
  __syncthreads();

  // ---------------- layer 0: K=3, pure VALU, float4 coord reads ----------------
  {
    const int c  = tid;
    const float w0 = W0[(s * 3 + 0) * 256 + c] * LOG2E;
    const float w1 = W0[(s * 3 + 1) * 256 + c] * LOG2E;
    const float w2 = W0[(s * 3 + 2) * 256 + c] * LOG2E;
    const float bb = b0[s * 256 + c] * LOG2E;
    const float4v* c4 = (const float4v*)cbuf;
    #pragma unroll
    for (int j = 0; j < 16; ++j) {             // rows 4j..4j+3, skew j*16
      float4v x0 = c4[j * 3 + 0];
      float4v x1 = c4[j * 3 + 1];
      float4v x2 = c4[j * 3 + 2];
      float z0 = fmaf(x0.z, w2, fmaf(x0.y, w1, fmaf(x0.x, w0, bb)));
      float z1 = fmaf(x1.y, w2, fmaf(x1.x, w1, fmaf(x0.w, w0, bb)));
      float z2 = fmaf(x2.x, w2, fmaf(x1.w, w1, fmaf(x1.z, w0, bb)));
      float z3 = fmaf(x2.w, w2, fmaf(x2.z, w1, fmaf(x2.y, w0, bb)));
      h_lds[(4 * j + 0) * HSTRIDE + j * 16 + c] = bf16_trunc(softplus_hat(z0));
      h_lds[(4 * j + 1) * HSTRIDE + j * 16 + c] = bf16_trunc(softplus_hat(z1));
      h_lds[(4 * j + 2) * HSTRIDE + j * 16 + c] = bf16_trunc(softplus_hat(z2));
      h_lds[(4 * j + 3) * HSTRIDE + j * 16 + c] = bf16_trunc(softplus_hat(z3));
    }
  }
  __syncthreads();

  const int colb = (wave << 6) + (lane & 15);
  const int q    = lane >> 4;
  const int lr   = lane & 15;
  // A-frag lane base: row lr (skew (lr>>2)*16), octet q. Imm: mi*MISTEP+kb*32.
  const unsigned short* aptr = h_lds + lr * HSTRIDE + (lr >> 2) * 16 + q * 8;
  // C-write lane base: rows q*4+r+16mi, col colb. addr = q*1072 + colb
  //                    + r*264 + mi*MISTEP (skew of row q*4+r+16mi = q+4mi).
  unsigned short* cptr = h_lds + q * 1072 + colb;

  const unsigned short* bbase0 = Wt + ((s << 2) << 16) + (colb << 5) + (q << 3);

  short8 bq[3][4];
  #pragma unroll
  for (int i = 0; i < 3; ++i)
    #pragma unroll
    for (int ni = 0; ni < 4; ++ni)
      bq[i][ni] = *(const short8*)(bbase0 + i * 8192 + ni * 512);

  float4v acc[4][4];
  const float* bh_s = bh + (s << 10);

  // ---------------- hidden layers 0..2 ----------------
  #define HIDDEN_LAYER(L)                                                     \
  {                                                                           \
    float bias[4];                                                            \
    _Pragma("unroll")                                                         \
    for (int ni = 0; ni < 4; ++ni)                                            \
      bias[ni] = bh_s[L * 256 + colb + ni * 16] * LOG2E;                      \
    _Pragma("unroll")                                                         \
    for (int mi = 0; mi < 4; ++mi)                                            \
      _Pragma("unroll")                                                       \
      for (int ni = 0; ni < 4; ++ni)                                          \
        acc[mi][ni] = (float4v){bias[ni], bias[ni], bias[ni], bias[ni]};      \
    hidden_mfma<L>(bbase0, aptr, bq, acc);                                    \
    _Pragma("unroll")                                                         \
    for (int mi = 0; mi < 4; ++mi)                                            \
      _Pragma("unroll")                                                       \
      for (int ni = 0; ni < 4; ++ni) {                                        \
        float4v v = acc[mi][ni];                                              \
        _Pragma("unroll")                                                     \
        for (int r = 0; r < 4; ++r) v[r] = softplus_hat(v[r]);                \
        acc[mi][ni] = v;                                                      \
      }                                                                       \
    __syncthreads();                                                          \
    _Pragma("unroll")                                                         \
    for (int mi = 0; mi < 4; ++mi)                                            \
      _Pragma("unroll")                                                       \
      for (int ni = 0; ni < 4; ++ni) {                                        \
        float4v v = acc[mi][ni];                                              \
        _Pragma("unroll")                                                     \
        for (int r = 0; r < 4; ++r)                                           \
          cptr[mi * MISTEP + r * HSTRIDE + ni * 16] = bf16_trunc(v[r]);       \
      }                                                                       \
    __syncthreads();                                                          \
  }

  HIDDEN_LAYER(0)
  HIDDEN_LAYER(1)
  HIDDEN_LAYER(2)
  #undef HIDDEN_LAYER

  // ------- layer 3: MFMA + fused output (dot with Wout, no h write-back) -------
  {
    float bias[4];
    #pragma unroll
    for (int ni = 0; ni < 4; ++ni)
      bias[ni] = bh_s[3 * 256 + colb + ni * 16] * LOG2E;
    #pragma unroll
    for (int mi = 0; mi < 4; ++mi)
      #pragma unroll
      for (int ni = 0; ni < 4; ++ni)
        acc[mi][ni] = (float4v){bias[ni], bias[ni], bias[ni], bias[ni]};

    hidden_mfma<3>(bbase0, aptr, bq, acc);

    // softplus + per-lane partial dot over this wave's 4 cols (fp32 h4).
    float wv[4];
    #pragma unroll
    for (int ni = 0; ni < 4; ++ni)
      wv[ni] = Wout[(s << 8) + colb + ni * 16];
    float p[16];
    #pragma unroll
    for (int i = 0; i < 16; ++i) p[i] = 0.f;
    #pragma unroll
    for (int mi = 0; mi < 4; ++mi)
      #pragma unroll
      for (int ni = 0; ni < 4; ++ni) {
        float4v v = acc[mi][ni];
        #pragma unroll
        for (int r = 0; r < 4; ++r)
          p[mi * 4 + r] = fmaf(softplus_hat(v[r]), wv[ni], p[mi * 4 + r]);
      }

    __syncthreads();                    // all A-reads done; h_lds reusable
    float* red = (float*)h_lds;         // 64 rows x 64 partials, stride-68 pad
    #pragma unroll
    for (int mi = 0; mi < 4; ++mi)
      #pragma unroll
      for (int r = 0; r < 4; ++r) {
        int row = mi * 16 + (q << 2) + r;
        red[row * 68 + (wave << 4) + (lane & 15)] = p[mi * 4 + r];
      }
    __syncthreads();

    if (tid < 64) {
      const float4v* rr = (const float4v*)&red[tid * 68];
      float4v a = rr[0];
      #pragma unroll
      for (int i = 1; i < 16; ++i) {
        float4v b = rr[i];
        a.x += b.x; a.y += b.y; a.z += b.z; a.w += b.w;
      }
      float tot = (a.x + a.y) + (a.z + a.w);
      out[(m0 + tid) * 8 + s] = fmaf(LN2, tot, bout[s]);  // undo log2-domain
    }
  }
}

// ---------------------------------------------------------------------------
// Fallback (scratch-free), fp32 VALU — only if ws_size < 4 MiB.
// ---------------------------------------------------------------------------
__global__ __launch_bounds__(256) void series_mlp_slow(
    const float* __restrict__ coords,
    const float* __restrict__ W0, const float* __restrict__ b0,
    const float* __restrict__ Wh, const float* __restrict__ bh,
    const float* __restrict__ Wout, const float* __restrict__ bout,
    float* __restrict__ out)
{
  __shared__ float hh[64 * 256];
  __shared__ float cbuf[192];
  __shared__ float red[256];
  const int tid = threadIdx.x;
  const int s   = blockIdx.y;
  const int m0  = blockIdx.x * 64;

  if (tid < 192) cbuf[tid] = coords[m0 * 3 + tid];
  __syncthreads();
  {
    const float w0 = W0[(s * 3 + 0) * 256 + tid];
    const float w1 = W0[(s * 3 + 1) * 256 + tid];
    const float w2 = W0[(s * 3 + 2) * 256 + tid];
    const float bb = b0[s * 256 + tid];
    for (int m = 0; m < 64; ++m) {
      float z = fmaf(cbuf[m * 3 + 2], w2,
                fmaf(cbuf[m * 3 + 1], w1,
                fmaf(cbuf[m * 3 + 0], w0, bb)));
      hh[m * 256 + tid] = LN2 * softplus_hat(z * LOG2E);
    }
  }
  __syncthreads();

  for (int l = 0; l < 4; ++l) {
    const float* W = Wh + (((s << 2) + l) << 16);
    const float bb = bh[((s << 2) + l) * 256 + tid];
    float acc[64];
    #pragma unroll
    for (int m = 0; m < 64; ++m) acc[m] = bb;
    for (int kc = 0; kc < 64; ++kc) {
      float w0 = W[(kc * 4 + 0) * 256 + tid];
      float w1 = W[(kc * 4 + 1) * 256 + tid];
      float w2 = W[(kc * 4 + 2) * 256 + tid];
      float w3 = W[(kc * 4 + 3) * 256 + tid];
      #pragma unroll
      for (int m = 0; m < 64; ++m) {
        float4v hv = *(const float4v*)&hh[m * 256 + kc * 4];
        acc[m] = fmaf(hv.w, w3, fmaf(hv.z, w2,
                 fmaf(hv.y, w1, fmaf(hv.x, w0, acc[m]))));
      }
    }
    __syncthreads();
    #pragma unroll
    for (int m = 0; m < 64; ++m)
      hh[m * 256 + tid] = LN2 * softplus_hat(acc[m] * LOG2E);
    __syncthreads();
  }
  {
    const int m = tid >> 2, qq = tid & 3;
    const float* wv = Wout + (s << 8);
    float sum = 0.f;
    for (int i = 0; i < 16; ++i) {
      int kk = (qq << 6) + ((((tid & 15) + i) << 2) & 63);
      float4v hv = *(const float4v*)&hh[m * 256 + kk];
      sum += hv.x * wv[kk] + hv.y * wv[kk + 1] + hv.z * wv[kk + 2] + hv.w * wv[kk + 3];
    }
    red[tid] = sum;
    __syncthreads();
    if (tid < 64)
      out[(m0 + tid) * 8 + s] =
          red[tid * 4] + red[tid * 4 + 1] + red[tid * 4 + 2] + red[tid * 4 + 3] + bout[s];
  }
}

extern "C" void kernel_launch(void* const* d_in, const int* in_sizes, int n_in,
                              void* d_out, int out_size, void* d_ws, size_t ws_size,
                              hipStream_t stream) {
  const float* coords = (const float*)d_in[0];
  const float* W0     = (const float*)d_in[1];
  const float* b0     = (const float*)d_in[2];
  const float* Wh     = (const float*)d_in[3];
  const float* bh     = (const float*)d_in[4];
  const float* Wout   = (const float*)d_in[5];
  const float* bout   = (const float*)d_in[6];
  float* out = (float*)d_out;

  const size_t WT_BYTES = (size_t)8 * 4 * 256 * 256 * 2;   // 4 MiB bf16 slabs
  if (ws_size >= WT_BYTES) {
    unsigned short* Wt = (unsigned short*)d_ws;
    convert_wh<<<8192, 256, 0, stream>>>(Wh, Wt);
    series_mlp<<<dim3(25000), dim3(256), 0, stream>>>(
        coords, W0, b0, bh, Wout, bout, Wt, out);
  } else {
    series_mlp_slow<<<dim3(3125, 8), dim3(256), 0, stream>>>(
        coords, W0, b0, Wh, bh, Wout, bout, out);
  }
  // second tuple output: echo coords
  hipMemcpyAsync(out + (size_t)200000 * 8, coords,
                 (size_t)200000 * 3 * sizeof(float),
                 hipMemcpyDeviceToDevice, stream);
}